// Round 3
// baseline (808.183 us; speedup 1.0000x reference)
//
#include <hip/hip_runtime.h>
#include <hip/hip_bf16.h>
#include <math.h>

#define NEG_SLOPE 0.2f
#define EPS_NRM 1e-12f
#define K_IN 256
#define C_OUT 64

// ---------------------------------------------------------------------------
// Kernel A: h = x @ W (+ fused a_src/a_dst scores).
// 4 threads per row, 16 output cols each. Same-address quad lanes merge in
// L1, so x traffic stays ~1x. Quad-local shfl_xor reduces the att dots.
// ---------------------------------------------------------------------------
__global__ __launch_bounds__(256) void gemm_att(
    const float* __restrict__ x, const float* __restrict__ W,
    const float* __restrict__ att_s, const float* __restrict__ att_d,
    float* __restrict__ h, float* __restrict__ a_src_arr,
    float* __restrict__ a_dst_arr, int N)
{
    int t = threadIdx.x;
    int q = t & 3;                        // output quarter (16 cols)
    int r = blockIdx.x * 64 + (t >> 2);   // row
    if (r >= N) return;

    float acc[16];
#pragma unroll
    for (int j = 0; j < 16; ++j) acc[j] = 0.f;

    const float* xr = x + (size_t)r * K_IN;
    const float* wq = W + q * 16;

    for (int k = 0; k < K_IN; k += 4) {
        float4 xv = *(const float4*)(xr + k);
#pragma unroll
        for (int kk = 0; kk < 4; ++kk) {
            float xs = (kk == 0) ? xv.x : (kk == 1) ? xv.y : (kk == 2) ? xv.z : xv.w;
            const float* wrow = wq + (size_t)(k + kk) * C_OUT;
#pragma unroll
            for (int j = 0; j < 4; ++j) {
                float4 wv = *(const float4*)(wrow + 4 * j);
                acc[4 * j + 0] += xs * wv.x;
                acc[4 * j + 1] += xs * wv.y;
                acc[4 * j + 2] += xs * wv.z;
                acc[4 * j + 3] += xs * wv.w;
            }
        }
    }

    float asum = 0.f, dsum = 0.f;
#pragma unroll
    for (int j = 0; j < 4; ++j) {
        float4 av = *(const float4*)(att_s + q * 16 + 4 * j);
        float4 dv = *(const float4*)(att_d + q * 16 + 4 * j);
        asum += acc[4 * j + 0] * av.x + acc[4 * j + 1] * av.y +
                acc[4 * j + 2] * av.z + acc[4 * j + 3] * av.w;
        dsum += acc[4 * j + 0] * dv.x + acc[4 * j + 1] * dv.y +
                acc[4 * j + 2] * dv.z + acc[4 * j + 3] * dv.w;
    }
    asum += __shfl_xor(asum, 1, 64); asum += __shfl_xor(asum, 2, 64);
    dsum += __shfl_xor(dsum, 1, 64); dsum += __shfl_xor(dsum, 2, 64);
    if (q == 0) { a_src_arr[r] = asum; a_dst_arr[r] = dsum; }

    float* hr = h + (size_t)r * C_OUT + q * 16;
#pragma unroll
    for (int j = 0; j < 4; ++j)
        *(float4*)(hr + 4 * j) = make_float4(acc[4 * j + 0], acc[4 * j + 1],
                                             acc[4 * j + 2], acc[4 * j + 3]);
}

// ---------------------------------------------------------------------------
// CSR build: histogram, 3-kernel scan (+1 for self loops), scatter.
// ---------------------------------------------------------------------------
__global__ __launch_bounds__(256) void count_dst(
    const int* __restrict__ dst, int* __restrict__ cnt, int E)
{
    int i = blockIdx.x * blockDim.x + threadIdx.x;
    if (i < E) atomicAdd(&cnt[dst[i]], 1);
}

__global__ __launch_bounds__(256) void scan_p1(
    const int* __restrict__ cnt, int* __restrict__ partials, int n)
{
    int b = blockIdx.x, t = threadIdx.x;
    int base = b * 1024;
    int s = 0;
#pragma unroll
    for (int j = 0; j < 4; ++j) {
        int i = base + t * 4 + j;
        if (i < n) s += cnt[i] + 1;  // +1 = self loop
    }
    for (int d = 1; d < 64; d <<= 1) s += __shfl_xor(s, d, 64);
    __shared__ int wsum[4];
    int lane = t & 63, wid = t >> 6;
    if (lane == 0) wsum[wid] = s;
    __syncthreads();
    if (t == 0) partials[b] = wsum[0] + wsum[1] + wsum[2] + wsum[3];
}

__global__ __launch_bounds__(256) void scan_p2(int* partials, int nb)
{
    __shared__ int buf[256];
    int t = threadIdx.x;
    int v = (t < nb) ? partials[t] : 0;
    buf[t] = v;
    __syncthreads();
    for (int d = 1; d < 256; d <<= 1) {
        int w = (t >= d) ? buf[t - d] : 0;
        __syncthreads();
        buf[t] += w;
        __syncthreads();
    }
    if (t < nb) partials[t] = buf[t] - v;  // exclusive
}

__global__ __launch_bounds__(256) void scan_p3(
    const int* __restrict__ cnt, const int* __restrict__ partials,
    int* __restrict__ offsets, int n)
{
    int b = blockIdx.x, t = threadIdx.x;
    int base = b * 1024;
    int v[4];
    int s = 0;
#pragma unroll
    for (int j = 0; j < 4; ++j) {
        int i = base + t * 4 + j;
        v[j] = (i < n) ? cnt[i] + 1 : 0;
        s += v[j];
    }
    int lane = t & 63, wid = t >> 6;
    int incl = s;
    for (int d = 1; d < 64; d <<= 1) {
        int w = __shfl_up(incl, d, 64);
        if (lane >= d) incl += w;
    }
    __shared__ int wsum[4];
    __shared__ int wbase[4];
    if (lane == 63) wsum[wid] = incl;
    __syncthreads();
    if (t == 0) {
        int r = 0;
        for (int i = 0; i < 4; ++i) { wbase[i] = r; r += wsum[i]; }
    }
    __syncthreads();
    int run = partials[b] + wbase[wid] + (incl - s);
#pragma unroll
    for (int j = 0; j < 4; ++j) {
        int i = base + t * 4 + j;
        if (i < n) {
            offsets[i] = run;
            run += v[j];
            if (i == n - 1) offsets[n] = run;
        }
    }
}

__global__ __launch_bounds__(256) void scatter_edges(
    const int* __restrict__ srcA, const int* __restrict__ dstA,
    const int* __restrict__ offsets, int* __restrict__ cursor,
    int* __restrict__ csr_src, int E, int N)
{
    int i = blockIdx.x * blockDim.x + threadIdx.x;
    if (i >= E + N) return;
    int s, d;
    if (i < E) { s = srcA[i]; d = dstA[i]; }
    else       { s = d = i - E; }
    int pos = offsets[d] + atomicAdd(&cursor[d], 1);
    csr_src[pos] = s;
}

// ---------------------------------------------------------------------------
// Kernel C: one wave per destination node; lane = output dim.
// Softmax without max-subtraction (scores bounded ~8, exp safe in fp32):
// w = exp(lrelu(a_src+a_dst)) computed in-loop, denominator accumulated
// in-loop. csr/a_src/h all prefetched one iteration ahead, 2-wide unroll.
// ---------------------------------------------------------------------------
__global__ __launch_bounds__(256) void gat_pull(
    const int* __restrict__ offsets, const int* __restrict__ csr_src,
    const float* __restrict__ h, const float* __restrict__ a_src,
    const float* __restrict__ a_dst, const float* __restrict__ bias,
    float* __restrict__ out, int N)
{
    int wid = (blockIdx.x * blockDim.x + threadIdx.x) >> 6;  // node id
    int lane = threadIdx.x & 63;
    if (wid >= N) return;

    int beg = offsets[wid];
    int n = offsets[wid + 1] - beg;       // >= 1 (self loop)
    const int* cs = csr_src + beg;
    float ad = a_dst[wid];

    // stage 0 of the pipeline
    int c0 = cs[0];
    int c1 = cs[(n > 1) ? 1 : 0];
    float as0 = a_src[c0];
    float as1 = a_src[c1];
    float hv0 = h[(size_t)c0 * C_OUT + lane];
    float hv1 = h[(size_t)c1 * C_OUT + lane];

    float acc0 = 0.f, acc1 = 0.f, den = 0.f;
    for (int p = 0; p < n; p += 2) {
        // prefetch next pair (clamped; harmless re-read of entry 0)
        int m0 = cs[(p + 2 < n) ? p + 2 : 0];
        int m1 = cs[(p + 3 < n) ? p + 3 : 0];
        float nas0 = a_src[m0];
        float nas1 = a_src[m1];
        float nhv0 = h[(size_t)m0 * C_OUT + lane];
        float nhv1 = h[(size_t)m1 * C_OUT + lane];

        float e0 = as0 + ad; e0 = fmaxf(e0, NEG_SLOPE * e0);
        float e1 = as1 + ad; e1 = fmaxf(e1, NEG_SLOPE * e1);
        float w0 = __expf(e0);
        float w1 = (p + 1 < n) ? __expf(e1) : 0.f;
        den  += w0 + w1;
        acc0 += w0 * hv0;
        acc1 += w1 * hv1;

        c0 = m0; c1 = m1; as0 = nas0; as1 = nas1; hv0 = nhv0; hv1 = nhv1;
    }

    float o = (acc0 + acc1) / den + bias[lane];

    float sq = o * o;
#pragma unroll
    for (int d = 1; d < 64; d <<= 1) sq += __shfl_xor(sq, d, 64);
    float nrm = fmaxf(sqrtf(sq), EPS_NRM);

    out[(size_t)wid * C_OUT + lane] = o / nrm;
}

// ---------------------------------------------------------------------------
extern "C" void kernel_launch(void* const* d_in, const int* in_sizes, int n_in,
                              void* d_out, int out_size, void* d_ws, size_t ws_size,
                              hipStream_t stream)
{
    const float* x     = (const float*)d_in[0];
    const int*   ei    = (const int*)d_in[1];   // [2][E], row0=src, row1=dst
    const float* W     = (const float*)d_in[2];
    const float* att_s = (const float*)d_in[3];
    const float* att_d = (const float*)d_in[4];
    const float* bias  = (const float*)d_in[5];
    float*       out   = (float*)d_out;

    const int OUT = in_sizes[3];          // 64
    const int IN  = in_sizes[2] / OUT;    // 256
    const int N   = in_sizes[0] / IN;     // 100000
    const int E   = in_sizes[1] / 2;      // 1600000

    // workspace carve-out (256B aligned) — total ~34.0 MB (round-1 level)
    char* w = (char*)d_ws;
    auto alloc = [&](size_t bytes) -> void* {
        void* p = (void*)w;
        w += (bytes + 255) & ~(size_t)255;
        return p;
    };
    float* h      = (float*)alloc((size_t)N * C_OUT * 4);
    float* a_src  = (float*)alloc((size_t)N * 4);
    float* a_dst  = (float*)alloc((size_t)N * 4);
    int*   cnt    = (int*)alloc((size_t)N * 4);   // histogram, reused as cursor
    int*   offs   = (int*)alloc((size_t)(N + 1) * 4);
    int*   parts  = (int*)alloc(1024 * 4);
    int*   csr    = (int*)alloc((size_t)(E + N) * 4);

    hipMemsetAsync(cnt, 0, (size_t)N * 4, stream);

    gemm_att<<<(N + 63) / 64, 256, 0, stream>>>(x, W, att_s, att_d,
                                                h, a_src, a_dst, N);

    count_dst<<<(E + 255) / 256, 256, 0, stream>>>(ei + E, cnt, E);

    int NB = (N + 1023) / 1024;
    scan_p1<<<NB, 256, 0, stream>>>(cnt, parts, N);
    scan_p2<<<1, 256, 0, stream>>>(parts, NB);
    scan_p3<<<NB, 256, 0, stream>>>(cnt, parts, offs, N);

    // reuse cnt as per-node scatter cursor
    hipMemsetAsync(cnt, 0, (size_t)N * 4, stream);

    scatter_edges<<<(E + N + 255) / 256, 256, 0, stream>>>(ei, ei + E, offs,
                                                           cnt, csr, E, N);

    gat_pull<<<(N + 3) / 4, 256, 0, stream>>>(offs, csr, h, a_src, a_dst,
                                              bias, out, N);
}

// Round 4
// 651.501 us; speedup vs baseline: 1.2405x; 1.2405x over previous
//
#include <hip/hip_runtime.h>
#include <hip/hip_bf16.h>
#include <math.h>

#define NEG_SLOPE 0.2f
#define EPS_NRM 1e-12f
#define K_IN 256
#define C_OUT 64

// ---------------------------------------------------------------------------
// Kernel A: h = x @ W (+ fused a_src/a_dst scores).
// Block stages W (64 KB) into LDS. One wave per 8 rows; lane = output col.
// Row addresses are wave-uniform (readfirstlane) -> x loads become
// s_load_dwordx4 (scalar cache broadcast, deep ILP). Per k: one conflict-free
// ds_read_b32 of W[k][lane] feeds 8 FMAs -> VALU-bound (~21 us floor).
// ---------------------------------------------------------------------------
__global__ __launch_bounds__(256) void gemm_att(
    const float* __restrict__ x, const float* __restrict__ W,
    const float* __restrict__ att_s, const float* __restrict__ att_d,
    float* __restrict__ h, float* __restrict__ a_src_arr,
    float* __restrict__ a_dst_arr, int N)
{
    __shared__ float Wl[K_IN * C_OUT];   // 64 KB, layout [k][col]

    int t = threadIdx.x;
    {   // coalesced staging: 16384 floats = 4096 float4, 16 per thread
        const float4* Wv = (const float4*)W;
        float4* Lv = (float4*)Wl;
#pragma unroll
        for (int i = 0; i < 16; ++i)
            Lv[i * 256 + t] = Wv[i * 256 + t];
    }
    __syncthreads();

    int lane = t & 63;
    int wslot = __builtin_amdgcn_readfirstlane(t >> 6);   // SGPR -> uniform
    int base_row = (blockIdx.x * 4 + wslot) * 8;
    if (base_row >= N) return;            // no further barriers below

    float att_sl = att_s[lane];
    float att_dl = att_d[lane];

    float acc[8];
#pragma unroll
    for (int r = 0; r < 8; ++r) acc[r] = 0.f;

    // clamped uniform row bases (tail-safe, stays scalar)
    const float* xr[8];
#pragma unroll
    for (int r = 0; r < 8; ++r) {
        int row = base_row + r; if (row >= N) row = N - 1;
        xr[r] = x + (size_t)row * K_IN;
    }

    for (int k = 0; k < K_IN; k += 4) {
        float4 xv[8];
#pragma unroll
        for (int r = 0; r < 8; ++r)
            xv[r] = *(const float4*)(xr[r] + k);          // s_load_dwordx4
#pragma unroll
        for (int kk = 0; kk < 4; ++kk) {
            float wv = Wl[(k + kk) * C_OUT + lane];       // ds_read, no conflict
#pragma unroll
            for (int r = 0; r < 8; ++r) {
                float xs = (kk == 0) ? xv[r].x : (kk == 1) ? xv[r].y
                         : (kk == 2) ? xv[r].z : xv[r].w;
                acc[r] += xs * wv;
            }
        }
    }

    int nvalid = N - base_row; if (nvalid > 8) nvalid = 8;
#pragma unroll
    for (int r = 0; r < 8; ++r) {
        if (r >= nvalid) break;
        float v = acc[r];
        float ps = v * att_sl;
        float pd = v * att_dl;
#pragma unroll
        for (int d = 1; d < 64; d <<= 1) {
            ps += __shfl_xor(ps, d, 64);
            pd += __shfl_xor(pd, d, 64);
        }
        int row = base_row + r;
        if (lane == 0) { a_src_arr[row] = ps; a_dst_arr[row] = pd; }
        h[(size_t)row * C_OUT + lane] = v;                // coalesced 256B
    }
}

// ---------------------------------------------------------------------------
// CSR build: histogram, 3-kernel scan (+1 for self loops), scatter.
// ---------------------------------------------------------------------------
__global__ __launch_bounds__(256) void count_dst(
    const int* __restrict__ dst, int* __restrict__ cnt, int E)
{
    int i = blockIdx.x * blockDim.x + threadIdx.x;
    if (i < E) atomicAdd(&cnt[dst[i]], 1);
}

__global__ __launch_bounds__(256) void scan_p1(
    const int* __restrict__ cnt, int* __restrict__ partials, int n)
{
    int b = blockIdx.x, t = threadIdx.x;
    int base = b * 1024;
    int s = 0;
#pragma unroll
    for (int j = 0; j < 4; ++j) {
        int i = base + t * 4 + j;
        if (i < n) s += cnt[i] + 1;  // +1 = self loop
    }
    for (int d = 1; d < 64; d <<= 1) s += __shfl_xor(s, d, 64);
    __shared__ int wsum[4];
    int lane = t & 63, wid = t >> 6;
    if (lane == 0) wsum[wid] = s;
    __syncthreads();
    if (t == 0) partials[b] = wsum[0] + wsum[1] + wsum[2] + wsum[3];
}

__global__ __launch_bounds__(256) void scan_p2(int* partials, int nb)
{
    __shared__ int buf[256];
    int t = threadIdx.x;
    int v = (t < nb) ? partials[t] : 0;
    buf[t] = v;
    __syncthreads();
    for (int d = 1; d < 256; d <<= 1) {
        int w = (t >= d) ? buf[t - d] : 0;
        __syncthreads();
        buf[t] += w;
        __syncthreads();
    }
    if (t < nb) partials[t] = buf[t] - v;  // exclusive
}

__global__ __launch_bounds__(256) void scan_p3(
    const int* __restrict__ cnt, const int* __restrict__ partials,
    int* __restrict__ offsets, int n)
{
    int b = blockIdx.x, t = threadIdx.x;
    int base = b * 1024;
    int v[4];
    int s = 0;
#pragma unroll
    for (int j = 0; j < 4; ++j) {
        int i = base + t * 4 + j;
        v[j] = (i < n) ? cnt[i] + 1 : 0;
        s += v[j];
    }
    int lane = t & 63, wid = t >> 6;
    int incl = s;
    for (int d = 1; d < 64; d <<= 1) {
        int w = __shfl_up(incl, d, 64);
        if (lane >= d) incl += w;
    }
    __shared__ int wsum[4];
    __shared__ int wbase[4];
    if (lane == 63) wsum[wid] = incl;
    __syncthreads();
    if (t == 0) {
        int r = 0;
        for (int i = 0; i < 4; ++i) { wbase[i] = r; r += wsum[i]; }
    }
    __syncthreads();
    int run = partials[b] + wbase[wid] + (incl - s);
#pragma unroll
    for (int j = 0; j < 4; ++j) {
        int i = base + t * 4 + j;
        if (i < n) {
            offsets[i] = run;
            run += v[j];
            if (i == n - 1) offsets[n] = run;
        }
    }
}

__global__ __launch_bounds__(256) void scatter_edges(
    const int* __restrict__ srcA, const int* __restrict__ dstA,
    const int* __restrict__ offsets, int* __restrict__ cursor,
    int* __restrict__ csr_src, int E, int N)
{
    int i = blockIdx.x * blockDim.x + threadIdx.x;
    if (i >= E + N) return;
    int s, d;
    if (i < E) { s = srcA[i]; d = dstA[i]; }
    else       { s = d = i - E; }
    int pos = offsets[d] + atomicAdd(&cursor[d], 1);
    csr_src[pos] = s;
}

// ---------------------------------------------------------------------------
// Kernel C: one wave per destination node; lane = output dim.
// Softmax without max-subtraction (scores bounded ~8, exp safe in fp32).
// ---------------------------------------------------------------------------
__global__ __launch_bounds__(256) void gat_pull(
    const int* __restrict__ offsets, const int* __restrict__ csr_src,
    const float* __restrict__ h, const float* __restrict__ a_src,
    const float* __restrict__ a_dst, const float* __restrict__ bias,
    float* __restrict__ out, int N)
{
    int wid = (blockIdx.x * blockDim.x + threadIdx.x) >> 6;  // node id
    int lane = threadIdx.x & 63;
    if (wid >= N) return;

    int beg = offsets[wid];
    int n = offsets[wid + 1] - beg;       // >= 1 (self loop)
    const int* cs = csr_src + beg;
    float ad = a_dst[wid];

    int c0 = cs[0];
    int c1 = cs[(n > 1) ? 1 : 0];
    float as0 = a_src[c0];
    float as1 = a_src[c1];
    float hv0 = h[(size_t)c0 * C_OUT + lane];
    float hv1 = h[(size_t)c1 * C_OUT + lane];

    float acc0 = 0.f, acc1 = 0.f, den = 0.f;
    for (int p = 0; p < n; p += 2) {
        int m0 = cs[(p + 2 < n) ? p + 2 : 0];
        int m1 = cs[(p + 3 < n) ? p + 3 : 0];
        float nas0 = a_src[m0];
        float nas1 = a_src[m1];
        float nhv0 = h[(size_t)m0 * C_OUT + lane];
        float nhv1 = h[(size_t)m1 * C_OUT + lane];

        float e0 = as0 + ad; e0 = fmaxf(e0, NEG_SLOPE * e0);
        float e1 = as1 + ad; e1 = fmaxf(e1, NEG_SLOPE * e1);
        float w0 = __expf(e0);
        float w1 = (p + 1 < n) ? __expf(e1) : 0.f;
        den  += w0 + w1;
        acc0 += w0 * hv0;
        acc1 += w1 * hv1;

        c0 = m0; c1 = m1; as0 = nas0; as1 = nas1; hv0 = nhv0; hv1 = nhv1;
    }

    float o = (acc0 + acc1) / den + bias[lane];

    float sq = o * o;
#pragma unroll
    for (int d = 1; d < 64; d <<= 1) sq += __shfl_xor(sq, d, 64);
    float nrm = fmaxf(sqrtf(sq), EPS_NRM);

    out[(size_t)wid * C_OUT + lane] = o / nrm;
}

// ---------------------------------------------------------------------------
extern "C" void kernel_launch(void* const* d_in, const int* in_sizes, int n_in,
                              void* d_out, int out_size, void* d_ws, size_t ws_size,
                              hipStream_t stream)
{
    const float* x     = (const float*)d_in[0];
    const int*   ei    = (const int*)d_in[1];   // [2][E], row0=src, row1=dst
    const float* W     = (const float*)d_in[2];
    const float* att_s = (const float*)d_in[3];
    const float* att_d = (const float*)d_in[4];
    const float* bias  = (const float*)d_in[5];
    float*       out   = (float*)d_out;

    const int OUT = in_sizes[3];          // 64
    const int IN  = in_sizes[2] / OUT;    // 256
    const int N   = in_sizes[0] / IN;     // 100000
    const int E   = in_sizes[1] / 2;      // 1600000

    // workspace carve-out (256B aligned) — ~34.0 MB total
    char* w = (char*)d_ws;
    auto alloc = [&](size_t bytes) -> void* {
        void* p = (void*)w;
        w += (bytes + 255) & ~(size_t)255;
        return p;
    };
    float* h      = (float*)alloc((size_t)N * C_OUT * 4);
    float* a_src  = (float*)alloc((size_t)N * 4);
    float* a_dst  = (float*)alloc((size_t)N * 4);
    int*   cnt    = (int*)alloc((size_t)N * 4);   // histogram, reused as cursor
    int*   offs   = (int*)alloc((size_t)(N + 1) * 4);
    int*   parts  = (int*)alloc(1024 * 4);
    int*   csr    = (int*)alloc((size_t)(E + N) * 4);

    hipMemsetAsync(cnt, 0, (size_t)N * 4, stream);

    // 32 rows per block (4 waves x 8 rows)
    gemm_att<<<(N + 31) / 32, 256, 0, stream>>>(x, W, att_s, att_d,
                                                h, a_src, a_dst, N);

    count_dst<<<(E + 255) / 256, 256, 0, stream>>>(ei + E, cnt, E);

    int NB = (N + 1023) / 1024;
    scan_p1<<<NB, 256, 0, stream>>>(cnt, parts, N);
    scan_p2<<<1, 256, 0, stream>>>(parts, NB);
    scan_p3<<<NB, 256, 0, stream>>>(cnt, parts, offs, N);

    // reuse cnt as per-node scatter cursor
    hipMemsetAsync(cnt, 0, (size_t)N * 4, stream);

    scatter_edges<<<(E + N + 255) / 256, 256, 0, stream>>>(ei, ei + E, offs,
                                                           cnt, csr, E, N);

    gat_pull<<<(N + 3) / 4, 256, 0, stream>>>(offs, csr, h, a_src, a_dst,
                                              bias, out, N);
}

// Round 5
// 444.058 us; speedup vs baseline: 1.8200x; 1.4672x over previous
//
#include <hip/hip_runtime.h>
#include <hip/hip_bf16.h>
#include <math.h>

#define NEG_SLOPE 0.2f
#define EPS_NRM 1e-12f
#define K_IN 256
#define C_OUT 64
#define BK 16
#define ROWS_PB 128

// ---------------------------------------------------------------------------
// Kernel A: h = x @ W (+ fused a_src/a_dst scores), h stored as bf16.
// 2D register tile: block = 256 thr, tile 128 rows x 64 cols, thread owns
// 8 rows x 4 cols (32 accs). x staged TRANSPOSED [k][row] so row-reads are
// ds_read_b128; W staged [k][col]. 12 KB LDS -> high occupancy. Per k-step:
// 3 b128 LDS reads (36 cyc) feed 32 FMAs (64 cyc) -> VALU-bound (~21us floor).
// ---------------------------------------------------------------------------
__global__ __launch_bounds__(256) void gemm_att(
    const float* __restrict__ x, const float* __restrict__ W,
    const float* __restrict__ att_s, const float* __restrict__ att_d,
    __hip_bfloat16* __restrict__ h, float* __restrict__ a_src_arr,
    float* __restrict__ a_dst_arr, int N)
{
    __shared__ float xt[BK][ROWS_PB];   // 8 KB, transposed
    __shared__ float wt[BK][C_OUT];     // 4 KB

    int t  = threadIdx.x;
    int tx = t & 15;          // col group: cols tx*4 .. tx*4+3
    int ty = t >> 4;          // row group: rows ty*8 .. ty*8+7
    int row0 = blockIdx.x * ROWS_PB;

    // staging roles
    int sr  = t >> 1;                 // x-stage row 0..127
    int skh = (t & 1) * 8;            // x-stage k-half 0 or 8
    int srow = row0 + sr; if (srow >= N) srow = N - 1;
    const float* xsp = x + (size_t)srow * K_IN + skh;

    float acc[8][4];
#pragma unroll
    for (int r = 0; r < 8; ++r)
#pragma unroll
        for (int c = 0; c < 4; ++c) acc[r][c] = 0.f;

    for (int k0 = 0; k0 < K_IN; k0 += BK) {
        // ---- stage x (transposed) : 2 float4 per thread ----
        float4 xa = *(const float4*)(xsp + k0);
        float4 xb = *(const float4*)(xsp + k0 + 4);
        // ---- stage W : 1 float4 per thread, layout preserved ----
        float4 wv4 = *(const float4*)(W + (size_t)k0 * C_OUT + t * 4);
        __syncthreads();   // previous tile fully consumed
        xt[skh + 0][sr] = xa.x; xt[skh + 1][sr] = xa.y;
        xt[skh + 2][sr] = xa.z; xt[skh + 3][sr] = xa.w;
        xt[skh + 4][sr] = xb.x; xt[skh + 5][sr] = xb.y;
        xt[skh + 6][sr] = xb.z; xt[skh + 7][sr] = xb.w;
        *(float4*)(&wt[0][0] + t * 4) = wv4;
        __syncthreads();

#pragma unroll
        for (int k = 0; k < BK; ++k) {
            float xv[8];
            *(float4*)&xv[0] = *(const float4*)&xt[k][ty * 8];
            *(float4*)&xv[4] = *(const float4*)&xt[k][ty * 8 + 4];
            float4 wv = *(const float4*)&wt[k][tx * 4];
#pragma unroll
            for (int r = 0; r < 8; ++r) {
                acc[r][0] += xv[r] * wv.x;
                acc[r][1] += xv[r] * wv.y;
                acc[r][2] += xv[r] * wv.z;
                acc[r][3] += xv[r] * wv.w;
            }
        }
    }

    // epilogue: att scores (reduce over 16 tx lanes) + bf16 h store
    float4 avl = *(const float4*)(att_s + tx * 4);
    float4 dvl = *(const float4*)(att_d + tx * 4);
#pragma unroll
    for (int r = 0; r < 8; ++r) {
        int row = row0 + ty * 8 + r;
        if (row >= N) continue;
        float ps = acc[r][0] * avl.x + acc[r][1] * avl.y +
                   acc[r][2] * avl.z + acc[r][3] * avl.w;
        float pd = acc[r][0] * dvl.x + acc[r][1] * dvl.y +
                   acc[r][2] * dvl.z + acc[r][3] * dvl.w;
#pragma unroll
        for (int d = 1; d < 16; d <<= 1) {
            ps += __shfl_xor(ps, d, 64);
            pd += __shfl_xor(pd, d, 64);
        }
        if (tx == 0) { a_src_arr[row] = ps; a_dst_arr[row] = pd; }
        __hip_bfloat16 hb[4];
#pragma unroll
        for (int c = 0; c < 4; ++c) hb[c] = __float2bfloat16(acc[r][c]);
        *(ushort2*)(h + (size_t)row * C_OUT + tx * 4) =
            make_ushort2(*(unsigned short*)&hb[0], *(unsigned short*)&hb[1]);
        *(ushort2*)(h + (size_t)row * C_OUT + tx * 4 + 2) =
            make_ushort2(*(unsigned short*)&hb[2], *(unsigned short*)&hb[3]);
    }
}

// ---------------------------------------------------------------------------
// CSR build: histogram, 3-kernel scan (+1 for self loops), fused scatter
// that also computes the edge softmax numerator w = exp(lrelu(as+ad)).
// ---------------------------------------------------------------------------
__global__ __launch_bounds__(256) void count_dst(
    const int* __restrict__ dst, int* __restrict__ cnt, int E)
{
    int i = blockIdx.x * blockDim.x + threadIdx.x;
    if (i < E) atomicAdd(&cnt[dst[i]], 1);
}

__global__ __launch_bounds__(256) void scan_p1(
    const int* __restrict__ cnt, int* __restrict__ partials, int n)
{
    int b = blockIdx.x, t = threadIdx.x;
    int base = b * 1024;
    int s = 0;
#pragma unroll
    for (int j = 0; j < 4; ++j) {
        int i = base + t * 4 + j;
        if (i < n) s += cnt[i] + 1;  // +1 = self loop
    }
    for (int d = 1; d < 64; d <<= 1) s += __shfl_xor(s, d, 64);
    __shared__ int wsum[4];
    int lane = t & 63, wid = t >> 6;
    if (lane == 0) wsum[wid] = s;
    __syncthreads();
    if (t == 0) partials[b] = wsum[0] + wsum[1] + wsum[2] + wsum[3];
}

__global__ __launch_bounds__(256) void scan_p2(int* partials, int nb)
{
    __shared__ int buf[256];
    int t = threadIdx.x;
    int v = (t < nb) ? partials[t] : 0;
    buf[t] = v;
    __syncthreads();
    for (int d = 1; d < 256; d <<= 1) {
        int w = (t >= d) ? buf[t - d] : 0;
        __syncthreads();
        buf[t] += w;
        __syncthreads();
    }
    if (t < nb) partials[t] = buf[t] - v;  // exclusive
}

__global__ __launch_bounds__(256) void scan_p3(
    const int* __restrict__ cnt, const int* __restrict__ partials,
    int* __restrict__ offsets, int n)
{
    int b = blockIdx.x, t = threadIdx.x;
    int base = b * 1024;
    int v[4];
    int s = 0;
#pragma unroll
    for (int j = 0; j < 4; ++j) {
        int i = base + t * 4 + j;
        v[j] = (i < n) ? cnt[i] + 1 : 0;
        s += v[j];
    }
    int lane = t & 63, wid = t >> 6;
    int incl = s;
    for (int d = 1; d < 64; d <<= 1) {
        int w = __shfl_up(incl, d, 64);
        if (lane >= d) incl += w;
    }
    __shared__ int wsum[4];
    __shared__ int wbase[4];
    if (lane == 63) wsum[wid] = incl;
    __syncthreads();
    if (t == 0) {
        int r = 0;
        for (int i = 0; i < 4; ++i) { wbase[i] = r; r += wsum[i]; }
    }
    __syncthreads();
    int run = partials[b] + wbase[wid] + (incl - s);
#pragma unroll
    for (int j = 0; j < 4; ++j) {
        int i = base + t * 4 + j;
        if (i < n) {
            offsets[i] = run;
            run += v[j];
            if (i == n - 1) offsets[n] = run;
        }
    }
}

// CSR entry: {src, w}. w = exp(lrelu(a_src+a_dst)) — no max-subtraction:
// scores bounded (~8) so exp is fp32-safe (verified rounds 3-4).
__global__ __launch_bounds__(256) void scatter_edges(
    const int* __restrict__ srcA, const int* __restrict__ dstA,
    const int* __restrict__ offsets, int* __restrict__ cursor,
    const float* __restrict__ a_src, const float* __restrict__ a_dst,
    int2* __restrict__ csr, int E, int N)
{
    int i = blockIdx.x * blockDim.x + threadIdx.x;
    if (i >= E + N) return;
    int s, d;
    if (i < E) { s = srcA[i]; d = dstA[i]; }
    else       { s = d = i - E; }
    float e = a_src[s] + a_dst[d];
    e = fmaxf(e, NEG_SLOPE * e);
    float w = __expf(e);
    int pos = offsets[d] + atomicAdd(&cursor[d], 1);
    int2 ent; ent.x = s; ent.y = __float_as_int(w);
    csr[pos] = ent;
}

// ---------------------------------------------------------------------------
// Kernel C: one wave per destination node; lane = output dim (bf16 gather,
// 128B/row). Weights precomputed -> per edge: uniform 8B csr load + gather +
// FMA + den add. 2-wide pipeline, one pair prefetched ahead.
// ---------------------------------------------------------------------------
__global__ __launch_bounds__(256) void gat_pull(
    const int* __restrict__ offsets, const int2* __restrict__ csr,
    const unsigned short* __restrict__ h, const float* __restrict__ bias,
    float* __restrict__ out, int N)
{
    int wid = (blockIdx.x * blockDim.x + threadIdx.x) >> 6;  // node id
    int lane = threadIdx.x & 63;
    if (wid >= N) return;

    int beg = offsets[wid];
    int n = offsets[wid + 1] - beg;       // >= 1 (self loop)
    const int2* ce = csr + beg;

    int2 c0 = ce[0];
    int2 c1 = ce[(n > 1) ? 1 : 0];
    unsigned short u0 = h[(size_t)c0.x * C_OUT + lane];
    unsigned short u1 = h[(size_t)c1.x * C_OUT + lane];

    float acc0 = 0.f, acc1 = 0.f, den = 0.f;
    for (int p = 0; p < n; p += 2) {
        int2 m0 = ce[(p + 2 < n) ? p + 2 : 0];
        int2 m1 = ce[(p + 3 < n) ? p + 3 : 0];
        unsigned short v0 = h[(size_t)m0.x * C_OUT + lane];
        unsigned short v1 = h[(size_t)m1.x * C_OUT + lane];

        float w0 = __int_as_float(c0.y);
        float w1 = (p + 1 < n) ? __int_as_float(c1.y) : 0.f;
        float hv0 = __uint_as_float((unsigned)u0 << 16);
        float hv1 = __uint_as_float((unsigned)u1 << 16);
        den  += w0 + w1;
        acc0 += w0 * hv0;
        acc1 += w1 * hv1;

        c0 = m0; c1 = m1; u0 = v0; u1 = v1;
    }

    float o = (acc0 + acc1) / den + bias[lane];

    float sq = o * o;
#pragma unroll
    for (int d = 1; d < 64; d <<= 1) sq += __shfl_xor(sq, d, 64);
    float nrm = fmaxf(sqrtf(sq), EPS_NRM);

    out[(size_t)wid * C_OUT + lane] = o / nrm;
}

// ---------------------------------------------------------------------------
extern "C" void kernel_launch(void* const* d_in, const int* in_sizes, int n_in,
                              void* d_out, int out_size, void* d_ws, size_t ws_size,
                              hipStream_t stream)
{
    const float* x     = (const float*)d_in[0];
    const int*   ei    = (const int*)d_in[1];   // [2][E], row0=src, row1=dst
    const float* W     = (const float*)d_in[2];
    const float* att_s = (const float*)d_in[3];
    const float* att_d = (const float*)d_in[4];
    const float* bias  = (const float*)d_in[5];
    float*       out   = (float*)d_out;

    const int OUT = in_sizes[3];          // 64
    const int IN  = in_sizes[2] / OUT;    // 256
    const int N   = in_sizes[0] / IN;     // 100000
    const int E   = in_sizes[1] / 2;      // 1600000

    // workspace carve-out (256B aligned) — ~28.3 MB total (< 34 MB known-safe)
    char* w = (char*)d_ws;
    auto alloc = [&](size_t bytes) -> void* {
        void* p = (void*)w;
        w += (bytes + 255) & ~(size_t)255;
        return p;
    };
    __hip_bfloat16* h = (__hip_bfloat16*)alloc((size_t)N * C_OUT * 2);
    float* a_src  = (float*)alloc((size_t)N * 4);
    float* a_dst  = (float*)alloc((size_t)N * 4);
    int*   cnt    = (int*)alloc((size_t)N * 2 * 4);  // [0..N) hist, [N..2N) cursor
    int*   offs   = (int*)alloc((size_t)(N + 1) * 4);
    int*   parts  = (int*)alloc(1024 * 4);
    int2*  csr    = (int2*)alloc((size_t)(E + N) * 8);
    int*   cursor = cnt + N;

    hipMemsetAsync(cnt, 0, (size_t)N * 2 * 4, stream);

    gemm_att<<<(N + ROWS_PB - 1) / ROWS_PB, 256, 0, stream>>>(
        x, W, att_s, att_d, h, a_src, a_dst, N);

    count_dst<<<(E + 255) / 256, 256, 0, stream>>>(ei + E, cnt, E);

    int NB = (N + 1023) / 1024;
    scan_p1<<<NB, 256, 0, stream>>>(cnt, parts, N);
    scan_p2<<<1, 256, 0, stream>>>(parts, NB);
    scan_p3<<<NB, 256, 0, stream>>>(cnt, parts, offs, N);

    scatter_edges<<<(E + N + 255) / 256, 256, 0, stream>>>(
        ei, ei + E, offs, cursor, a_src, a_dst, csr, E, N);

    gat_pull<<<(N + 3) / 4, 256, 0, stream>>>(offs, csr,
        (const unsigned short*)h, bias, out, N);
}

// Round 6
// 403.421 us; speedup vs baseline: 2.0033x; 1.1007x over previous
//
#include <hip/hip_runtime.h>
#include <hip/hip_bf16.h>
#include <math.h>

#define NEG_SLOPE 0.2f
#define EPS_NRM 1e-12f
#define K_IN 256
#define C_OUT 64
#define BK 32
#define ROWS_PB 128

// ---------------------------------------------------------------------------
// Kernel A: h = x @ W (+ fused a_src/a_dst scores), h stored as bf16.
// 2D register tile: 256 thr, tile 128 rows x 64 cols, thread owns 8x4 accs.
// x staged TRANSPOSED [k][row] (b128 reads); W staged [k][col]. BK=32
// (24 KB LDS) halves barrier count vs BK=16; 32 FMAs per k-step/thread.
// ---------------------------------------------------------------------------
__global__ __launch_bounds__(256) void gemm_att(
    const float* __restrict__ x, const float* __restrict__ W,
    const float* __restrict__ att_s, const float* __restrict__ att_d,
    __hip_bfloat16* __restrict__ h, float* __restrict__ a_src_arr,
    float* __restrict__ a_dst_arr, int N)
{
    __shared__ float xt[BK][ROWS_PB];   // 16 KB, transposed
    __shared__ float wt[BK][C_OUT];     // 8 KB

    int t  = threadIdx.x;
    int tx = t & 15;          // col group: cols tx*4 .. tx*4+3
    int ty = t >> 4;          // row group: rows ty*8 .. ty*8+7
    int row0 = blockIdx.x * ROWS_PB;

    // staging roles: thread stages k-halves [skh, skh+16) of row sr
    int sr  = t >> 1;
    int skh = (t & 1) * 16;
    int srow = row0 + sr; if (srow >= N) srow = N - 1;
    const float* xsp = x + (size_t)srow * K_IN + skh;

    float acc[8][4];
#pragma unroll
    for (int r = 0; r < 8; ++r)
#pragma unroll
        for (int c = 0; c < 4; ++c) acc[r][c] = 0.f;

    for (int k0 = 0; k0 < K_IN; k0 += BK) {
        float4 xa = *(const float4*)(xsp + k0);
        float4 xb = *(const float4*)(xsp + k0 + 4);
        float4 xc = *(const float4*)(xsp + k0 + 8);
        float4 xd = *(const float4*)(xsp + k0 + 12);
        float4 wv4a = *(const float4*)(W + (size_t)k0 * C_OUT + t * 4);
        float4 wv4b = *(const float4*)(W + (size_t)(k0 + 16) * C_OUT + t * 4);
        __syncthreads();   // previous tile fully consumed
        xt[skh +  0][sr] = xa.x; xt[skh +  1][sr] = xa.y;
        xt[skh +  2][sr] = xa.z; xt[skh +  3][sr] = xa.w;
        xt[skh +  4][sr] = xb.x; xt[skh +  5][sr] = xb.y;
        xt[skh +  6][sr] = xb.z; xt[skh +  7][sr] = xb.w;
        xt[skh +  8][sr] = xc.x; xt[skh +  9][sr] = xc.y;
        xt[skh + 10][sr] = xc.z; xt[skh + 11][sr] = xc.w;
        xt[skh + 12][sr] = xd.x; xt[skh + 13][sr] = xd.y;
        xt[skh + 14][sr] = xd.z; xt[skh + 15][sr] = xd.w;
        *(float4*)(&wt[ 0][0] + t * 4) = wv4a;
        *(float4*)(&wt[16][0] + t * 4) = wv4b;
        __syncthreads();

#pragma unroll
        for (int k = 0; k < BK; ++k) {
            float xv[8];
            *(float4*)&xv[0] = *(const float4*)&xt[k][ty * 8];
            *(float4*)&xv[4] = *(const float4*)&xt[k][ty * 8 + 4];
            float4 wv = *(const float4*)&wt[k][tx * 4];
#pragma unroll
            for (int r = 0; r < 8; ++r) {
                acc[r][0] += xv[r] * wv.x;
                acc[r][1] += xv[r] * wv.y;
                acc[r][2] += xv[r] * wv.z;
                acc[r][3] += xv[r] * wv.w;
            }
        }
    }

    // epilogue: att scores (reduce over 16 tx lanes) + bf16 h store
    float4 avl = *(const float4*)(att_s + tx * 4);
    float4 dvl = *(const float4*)(att_d + tx * 4);
#pragma unroll
    for (int r = 0; r < 8; ++r) {
        int row = row0 + ty * 8 + r;
        if (row >= N) continue;
        float ps = acc[r][0] * avl.x + acc[r][1] * avl.y +
                   acc[r][2] * avl.z + acc[r][3] * avl.w;
        float pd = acc[r][0] * dvl.x + acc[r][1] * dvl.y +
                   acc[r][2] * dvl.z + acc[r][3] * dvl.w;
#pragma unroll
        for (int d = 1; d < 16; d <<= 1) {
            ps += __shfl_xor(ps, d, 64);
            pd += __shfl_xor(pd, d, 64);
        }
        if (tx == 0) { a_src_arr[row] = ps; a_dst_arr[row] = pd; }
        __hip_bfloat16 hb[4];
#pragma unroll
        for (int c = 0; c < 4; ++c) hb[c] = __float2bfloat16(acc[r][c]);
        *(ushort2*)(h + (size_t)row * C_OUT + tx * 4) =
            make_ushort2(*(unsigned short*)&hb[0], *(unsigned short*)&hb[1]);
        *(ushort2*)(h + (size_t)row * C_OUT + tx * 4 + 2) =
            make_ushort2(*(unsigned short*)&hb[2], *(unsigned short*)&hb[3]);
    }
}

// ---------------------------------------------------------------------------
// CSR build: histogram, 3-kernel scan (+1 for self loops), fused scatter
// that also computes the edge softmax numerator w = exp(lrelu(as+ad)).
// ---------------------------------------------------------------------------
__global__ __launch_bounds__(256) void count_dst(
    const int* __restrict__ dst, int* __restrict__ cnt, int E)
{
    int i = blockIdx.x * blockDim.x + threadIdx.x;
    if (i < E) atomicAdd(&cnt[dst[i]], 1);
}

__global__ __launch_bounds__(256) void scan_p1(
    const int* __restrict__ cnt, int* __restrict__ partials, int n)
{
    int b = blockIdx.x, t = threadIdx.x;
    int base = b * 1024;
    int s = 0;
#pragma unroll
    for (int j = 0; j < 4; ++j) {
        int i = base + t * 4 + j;
        if (i < n) s += cnt[i] + 1;  // +1 = self loop
    }
    for (int d = 1; d < 64; d <<= 1) s += __shfl_xor(s, d, 64);
    __shared__ int wsum[4];
    int lane = t & 63, wid = t >> 6;
    if (lane == 0) wsum[wid] = s;
    __syncthreads();
    if (t == 0) partials[b] = wsum[0] + wsum[1] + wsum[2] + wsum[3];
}

__global__ __launch_bounds__(256) void scan_p2(int* partials, int nb)
{
    __shared__ int buf[256];
    int t = threadIdx.x;
    int v = (t < nb) ? partials[t] : 0;
    buf[t] = v;
    __syncthreads();
    for (int d = 1; d < 256; d <<= 1) {
        int w = (t >= d) ? buf[t - d] : 0;
        __syncthreads();
        buf[t] += w;
        __syncthreads();
    }
    if (t < nb) partials[t] = buf[t] - v;  // exclusive
}

__global__ __launch_bounds__(256) void scan_p3(
    const int* __restrict__ cnt, const int* __restrict__ partials,
    int* __restrict__ offsets, int n)
{
    int b = blockIdx.x, t = threadIdx.x;
    int base = b * 1024;
    int v[4];
    int s = 0;
#pragma unroll
    for (int j = 0; j < 4; ++j) {
        int i = base + t * 4 + j;
        v[j] = (i < n) ? cnt[i] + 1 : 0;
        s += v[j];
    }
    int lane = t & 63, wid = t >> 6;
    int incl = s;
    for (int d = 1; d < 64; d <<= 1) {
        int w = __shfl_up(incl, d, 64);
        if (lane >= d) incl += w;
    }
    __shared__ int wsum[4];
    __shared__ int wbase[4];
    if (lane == 63) wsum[wid] = incl;
    __syncthreads();
    if (t == 0) {
        int r = 0;
        for (int i = 0; i < 4; ++i) { wbase[i] = r; r += wsum[i]; }
    }
    __syncthreads();
    int run = partials[b] + wbase[wid] + (incl - s);
#pragma unroll
    for (int j = 0; j < 4; ++j) {
        int i = base + t * 4 + j;
        if (i < n) {
            offsets[i] = run;
            run += v[j];
            if (i == n - 1) offsets[n] = run;
        }
    }
}

// CSR entry: {src, w}. w = exp(lrelu(a_src+a_dst)) — no max-subtraction:
// scores bounded (~8) so exp is fp32-safe (verified rounds 3-5).
__global__ __launch_bounds__(256) void scatter_edges(
    const int* __restrict__ srcA, const int* __restrict__ dstA,
    const int* __restrict__ offsets, int* __restrict__ cursor,
    const float* __restrict__ a_src, const float* __restrict__ a_dst,
    int2* __restrict__ csr, int E, int N)
{
    int i = blockIdx.x * blockDim.x + threadIdx.x;
    if (i >= E + N) return;
    int s, d;
    if (i < E) { s = srcA[i]; d = dstA[i]; }
    else       { s = d = i - E; }
    float e = a_src[s] + a_dst[d];
    e = fmaxf(e, NEG_SLOPE * e);
    float w = __expf(e);
    int pos = offsets[d] + atomicAdd(&cursor[d], 1);
    int2 ent; ent.x = s; ent.y = __float_as_int(w);
    csr[pos] = ent;
}

// ---------------------------------------------------------------------------
// Kernel C: HALF-WAVE per destination node — lanes 0-31 = node A, 32-63 =
// node B; each lane covers 2 bf16 output cols via one uint load. Every loop
// instruction serves 2 nodes -> wave-level VALU per edge halves vs round 5.
// Per-half shfl_xor (d<=16) for the L2 norm; float2 coalesced stores.
// ---------------------------------------------------------------------------
__global__ __launch_bounds__(256) void gat_pull(
    const int* __restrict__ offsets, const int2* __restrict__ csr,
    const unsigned short* __restrict__ h, const float* __restrict__ bias,
    float* __restrict__ out, int N)
{
    int gw   = (blockIdx.x * blockDim.x + threadIdx.x) >> 6;  // wave id
    int lane = threadIdx.x & 63;
    int half = lane >> 5;
    int hl   = lane & 31;
    int node = gw * 2 + half;
    bool valid = node < N;
    int nv = valid ? node : 0;

    int beg = offsets[nv];
    int n   = valid ? (offsets[nv + 1] - beg) : 0;   // >= 1 when valid
    const int2* ce = csr + beg;

    float2 bl = *(const float2*)(bias + 2 * hl);

    int2 c0 = ce[0];                       // safe: every node has >=1 entry
    int2 c1 = ce[(n > 1) ? 1 : 0];
    unsigned u0 = *(const unsigned*)(h + (size_t)c0.x * C_OUT + 2 * hl);
    unsigned u1 = *(const unsigned*)(h + (size_t)c1.x * C_OUT + 2 * hl);

    float a00 = 0.f, a01 = 0.f, a10 = 0.f, a11 = 0.f, den = 0.f;
    for (int p = 0; p < n; p += 2) {       // divergent between halves: ok
        int2 m0 = ce[(p + 2 < n) ? p + 2 : 0];
        int2 m1 = ce[(p + 3 < n) ? p + 3 : 0];
        unsigned v0 = *(const unsigned*)(h + (size_t)m0.x * C_OUT + 2 * hl);
        unsigned v1 = *(const unsigned*)(h + (size_t)m1.x * C_OUT + 2 * hl);

        float w0 = __int_as_float(c0.y);
        float w1 = (p + 1 < n) ? __int_as_float(c1.y) : 0.f;
        float h00 = __uint_as_float(u0 << 16);
        float h01 = __uint_as_float(u0 & 0xffff0000u);
        float h10 = __uint_as_float(u1 << 16);
        float h11 = __uint_as_float(u1 & 0xffff0000u);
        den += w0 + w1;
        a00 += w0 * h00; a01 += w0 * h01;
        a10 += w1 * h10; a11 += w1 * h11;

        c0 = m0; c1 = m1; u0 = v0; u1 = v1;
    }

    float o0 = (a00 + a10) / den + bl.x;
    float o1 = (a01 + a11) / den + bl.y;

    // L2 norm within each 32-lane half (xor d=1..16 stays inside the half)
    float sq = o0 * o0 + o1 * o1;
#pragma unroll
    for (int d = 1; d < 32; d <<= 1) sq += __shfl_xor(sq, d, 64);
    float nrm = fmaxf(sqrtf(sq), EPS_NRM);

    if (valid)
        *(float2*)(out + (size_t)node * C_OUT + 2 * hl) =
            make_float2(o0 / nrm, o1 / nrm);
}

// ---------------------------------------------------------------------------
extern "C" void kernel_launch(void* const* d_in, const int* in_sizes, int n_in,
                              void* d_out, int out_size, void* d_ws, size_t ws_size,
                              hipStream_t stream)
{
    const float* x     = (const float*)d_in[0];
    const int*   ei    = (const int*)d_in[1];   // [2][E], row0=src, row1=dst
    const float* W     = (const float*)d_in[2];
    const float* att_s = (const float*)d_in[3];
    const float* att_d = (const float*)d_in[4];
    const float* bias  = (const float*)d_in[5];
    float*       out   = (float*)d_out;

    const int OUT = in_sizes[3];          // 64
    const int IN  = in_sizes[2] / OUT;    // 256
    const int N   = in_sizes[0] / IN;     // 100000
    const int E   = in_sizes[1] / 2;      // 1600000

    // workspace carve-out (256B aligned) — ~28.3 MB total (< 34 MB known-safe)
    char* w = (char*)d_ws;
    auto alloc = [&](size_t bytes) -> void* {
        void* p = (void*)w;
        w += (bytes + 255) & ~(size_t)255;
        return p;
    };
    __hip_bfloat16* h = (__hip_bfloat16*)alloc((size_t)N * C_OUT * 2);
    float* a_src  = (float*)alloc((size_t)N * 4);
    float* a_dst  = (float*)alloc((size_t)N * 4);
    int*   cnt    = (int*)alloc((size_t)N * 2 * 4);  // [0..N) hist, [N..2N) cursor
    int*   offs   = (int*)alloc((size_t)(N + 1) * 4);
    int*   parts  = (int*)alloc(1024 * 4);
    int2*  csr    = (int2*)alloc((size_t)(E + N) * 8);
    int*   cursor = cnt + N;

    hipMemsetAsync(cnt, 0, (size_t)N * 2 * 4, stream);

    gemm_att<<<(N + ROWS_PB - 1) / ROWS_PB, 256, 0, stream>>>(
        x, W, att_s, att_d, h, a_src, a_dst, N);

    count_dst<<<(E + 255) / 256, 256, 0, stream>>>(ei + E, cnt, E);

    int NB = (N + 1023) / 1024;
    scan_p1<<<NB, 256, 0, stream>>>(cnt, parts, N);
    scan_p2<<<1, 256, 0, stream>>>(parts, NB);
    scan_p3<<<NB, 256, 0, stream>>>(cnt, parts, offs, N);

    scatter_edges<<<(E + N + 255) / 256, 256, 0, stream>>>(
        ei, ei + E, offs, cursor, a_src, a_dst, csr, E, N);

    // one wave per 2 nodes -> ceil(N/2) waves -> /8 nodes per 256-thr block
    gat_pull<<<(N + 7) / 8, 256, 0, stream>>>(offs, csr,
        (const unsigned short*)h, bias, out, N);
}